// Round 18
// baseline (51.865 us; speedup 1.0000x reference)
//
#include <hip/hip_runtime.h>

typedef __attribute__((ext_vector_type(8))) short bfrag;   // 8 bf16 = 4 VGPR
typedef __attribute__((ext_vector_type(4))) float f32x4;

namespace {
constexpr int N_ = 16, C_ = 112, H_ = 48, W_ = 48, HW_ = 2304;
constexpr int NKS = 18;  // K-slices of 128 (18*128 = 2304)
// ws float offsets
constexpr int WS_T7 = 0;          // 768
constexpr int WS_GF = 4096;       // f32 S' accum: 16*112*128 = 229376 -> 233472
constexpr int WS_WPACK = 233472;  // 3*112*128 bf16 = 21504 f -> 254976
constexpr int GF_TOT = 229376;
}

__device__ __forceinline__ float f4e(const float4& v, int e) {
  return e == 0 ? v.x : e == 1 ? v.y : e == 2 ? v.z : v.w;
}
__device__ __forceinline__ unsigned f2bf(float f) {  // RNE, low 16 bits
  unsigned u = __float_as_uint(f);
  return (u + 0x7FFFu + ((u >> 16) & 1u)) >> 16;
}
__device__ __forceinline__ float bf2f(unsigned short s) {
  return __uint_as_float(((unsigned)s) << 16);
}

// ---------------------------------------------------------------------------
// K1: t7 projection (coalesced) + zero the f32 G-accumulator (re-done every
// call so graph replays accumulate from zero). grid (48,16), 192 thr.
__global__ __launch_bounds__(192) void ath_t7(const float* __restrict__ x,
                                              const float* __restrict__ p7,
                                              float* __restrict__ ws) {
  const int h = blockIdx.x, n = blockIdx.y;
  const int tid = threadIdx.x;
  // zero G-accumulator (independent of t7 math; gram runs in a later kernel)
  {
    int lb = (blockIdx.y * 48 + blockIdx.x) * 192 + tid;
    for (int i = lb; i < GF_TOT; i += 768 * 192) ws[WS_GF + i] = 0.f;
  }
  __shared__ float q[48];
  __shared__ float wred[3];
  if (tid < 48) {
    float s = 0.f;
#pragma unroll
    for (int k = 0; k < 3; ++k) {
      int wp = tid + 3 - 3 * k;
      if (wp >= 0 && wp < 48) s += p7[k * 48 + wp];
    }
    q[tid] = s;
  }
  __syncthreads();
  const int c16 = tid / 12, qq = tid - 12 * c16;
  const float qv0 = q[4 * qq], qv1 = q[4 * qq + 1];
  const float qv2 = q[4 * qq + 2], qv3 = q[4 * qq + 3];
  float d = 0.f;
#pragma unroll
  for (int p = 0; p < 7; ++p) {
    const int c = c16 + 16 * p;
    float4 v = *(const float4*)&x[((size_t)n * C_ + c) * HW_ + h * W_ + 4 * qq];
    d += v.x * qv0 + v.y * qv1 + v.z * qv2 + v.w * qv3;
  }
#pragma unroll
  for (int off = 32; off >= 1; off >>= 1) d += __shfl_xor(d, off);
  if ((tid & 63) == 0) wred[tid >> 6] = d;
  __syncthreads();
  if (tid == 0)
    ws[WS_T7 + n * H_ + (h + 2) % 48] =
        (wred[0] + wred[1] + wred[2]) * (1.0f / 112.0f);
}

// ---------------------------------------------------------------------------
// K2: Gram via MFMA, st17-augmented A (LDS) x raw-x B (register-prefetched),
// virtual t7 B-row (col 112 = A1+A2 for A'). Partials go straight into the
// f32 G-accumulator via device-scope atomicAdd (no SPART round-trip, no
// assemble kernel). Tail blocks: wpack. grid 576 + 42, 256 threads.
__global__ __launch_bounds__(256) void ath_gram(const float* __restrict__ x,
                                                const float* __restrict__ cw,
                                                float* __restrict__ ws) {
  const int bid = blockIdx.x;
  const int tid = threadIdx.x;
  if (bid >= 2 * NKS * N_) {  // ---- wpack tail: bf16 [kx][o][i pad 128]
    int idx = (bid - 2 * NKS * N_) * 256 + tid;
    if (idx < 3 * 112 * 32) {
      int kx = idx / (112 * 32);
      int r = idx - kx * 112 * 32;
      int o = r >> 5;
      int i0 = (r & 31) * 4;
      unsigned short v[4];
#pragma unroll
      for (int e = 0; e < 4; ++e) {
        int i = i0 + e;
        v[e] = (i < 112) ? (unsigned short)f2bf(cw[o * 336 + i * 3 + kx])
                         : (unsigned short)0;
      }
      unsigned short* wp = (unsigned short*)(ws + WS_WPACK);
      *(ushort4*)&wp[(kx * 112 + o) * 128 + i0] = make_ushort4(v[0], v[1], v[2], v[3]);
    }
    return;
  }
  const int half = bid & 1;
  const int ks = (bid >> 1) % NKS;
  const int n = bid / (2 * NKS);
  const int k0 = ks * 128;
  const int lane = tid & 63, wv = tid >> 6;
  const int lr = lane & 15, lg = lane >> 4;
  __shared__ __align__(16) unsigned short As[112][136];
  __shared__ __align__(16) unsigned short t7r[136];
  __shared__ float t7s[48];
  __shared__ float s17[8];
  if (tid < 48) t7s[tid] = ws[WS_T7 + n * H_ + tid];
  __syncthreads();
  if (tid < 7) {  // t17[kk] = (1/48) sum_h |t7pad[2kk+h-6]|
    float s = 0.f;
    for (int hh = 0; hh < 48; ++hh) {
      int j = 2 * tid + hh - 6;
      if (j >= 0 && j < 48) s += fabsf(t7s[j]);
    }
    s17[tid] = s * (1.0f / 48.0f);
  }
  if (tid >= 64 && tid < 192)
    t7r[tid - 64] = (unsigned short)f2bf(t7s[(k0 + tid - 64) / 48]);
  if (tid >= 192 && tid < 200) t7r[128 + (tid - 192)] = 0;
  // prefetch B fragments into registers (no LDS dependency; overlaps)
  const int ti = wv + 4 * half;  // this wave's output column-group (0..7)
  bfrag breg[4];
  if (ti < 7) {
    const float* bp = &x[((size_t)n * C_ + 16 * ti + lr) * HW_ + k0 + 8 * lg];
#pragma unroll
    for (int kb = 0; kb < 4; ++kb) {
      float4 v0 = *(const float4*)(bp + 32 * kb);
      float4 v1 = *(const float4*)(bp + 32 * kb + 4);
      breg[kb][0] = (short)f2bf(v0.x); breg[kb][1] = (short)f2bf(v0.y);
      breg[kb][2] = (short)f2bf(v0.z); breg[kb][3] = (short)f2bf(v0.w);
      breg[kb][4] = (short)f2bf(v1.x); breg[kb][5] = (short)f2bf(v1.y);
      breg[kb][6] = (short)f2bf(v1.z); breg[kb][7] = (short)f2bf(v1.w);
    }
  }
  __syncthreads();  // s17/t7r visible to ALL waves before A staging reads s17
  // stage augmented A: As[c][p-k0] = bf16(x[c,p] + s17[(c+p)%7])
  const int kq = tid & 31, cg2 = tid >> 5;
  const int base7 = (k0 + 4 * kq) % 7;
#pragma unroll
  for (int r = 0; r < 14; ++r) {
    const int c = cg2 + 8 * r;
    float4 v = *(const float4*)&x[((size_t)n * C_ + c) * HW_ + k0 + 4 * kq];
    int cls0 = (base7 + c) % 7;
    unsigned short a4[4];
#pragma unroll
    for (int e = 0; e < 4; ++e) {
      int cl = cls0 + e;
      cl = (cl >= 7) ? cl - 7 : cl;
      a4[e] = (unsigned short)f2bf(f4e(v, e) + s17[cl]);
    }
    *(ushort4*)&As[c][4 * kq] = make_ushort4(a4[0], a4[1], a4[2], a4[3]);
  }
  __syncthreads();
  if (ti == 7) {
    const bfrag zero8 = {0, 0, 0, 0, 0, 0, 0, 0};
#pragma unroll
    for (int kb = 0; kb < 4; ++kb)
      breg[kb] = (lr == 0) ? *(const bfrag*)&t7r[8 * lg + 32 * kb] : zero8;
  }
  f32x4 acc[7];
#pragma unroll
  for (int j = 0; j < 7; ++j) acc[j] = (f32x4){0.f, 0.f, 0.f, 0.f};
#pragma unroll
  for (int kb = 0; kb < 4; ++kb) {
#pragma unroll
    for (int tc = 0; tc < 7; ++tc) {
      bfrag a = *(const bfrag*)&As[16 * tc + lr][8 * lg + 32 * kb];
      acc[tc] = __builtin_amdgcn_mfma_f32_16x16x32_bf16(a, breg[kb], acc[tc], 0, 0, 0);
    }
  }
  float* gf = ws + WS_GF + (size_t)n * 14336;
#pragma unroll
  for (int tc = 0; tc < 7; ++tc)
#pragma unroll
    for (int e = 0; e < 4; ++e)
      atomicAdd(&gf[(16 * tc + 4 * lg + e) * 128 + 16 * ti + lr], acc[tc][e]);
}

// ---------------------------------------------------------------------------
// K3 fused via MFMA, LDS-stationary operands (R13 structure). Reads the f32
// G-accumulator directly: bf16-convert during buf staging; p19*scale applied
// to the f32 output accumulator (per-row c, folds out of the MFMA); A' from
// column 112. xT[52][136]; buf[112][136]; t13 in-place. LDS ~45.5 KB.
__global__ __launch_bounds__(256) void ath_fused(const float* __restrict__ x,
                                                 const float* __restrict__ p19,
                                                 const float* __restrict__ ws,
                                                 float* __restrict__ out) {
  const int h = blockIdx.x, n = blockIdx.y;
  const int tid = threadIdx.x;
  const int lane = tid & 63, wv = tid >> 6;
  const int lr = lane & 15, lg = lane >> 4;
  __shared__ __align__(16) unsigned short xT[52][136];
  __shared__ __align__(16) unsigned short buf[112][136];
  __shared__ float sA[112];
  __shared__ float sP[112];
  const float* xb = x + (size_t)n * C_ * HW_ + h * W_;
  const unsigned short* wp = (const unsigned short*)(ws + WS_WPACK);
  const float* gf = ws + WS_GF + (size_t)n * 14336;
  // zero pads
  for (int idx = tid; idx < 52 * 24; idx += 256) {
    int r2 = idx / 24, cc = 112 + idx % 24;
    xT[r2][cc] = 0;
  }
  for (int idx = tid; idx < 4 * 112; idx += 256) {
    int rr = idx / 112;
    int r2 = (rr < 2) ? rr : 48 + rr;
    xT[r2][idx % 112] = 0;
  }
  if (tid < 112) {
    const float scale = 1.0f / (48.0f * sqrtf(112.0f));
    float pc = p19[tid];
    sA[tid] = pc * gf[tid * 128 + 112] * (2.0f / 48.0f);
    sP[tid] = pc * scale;
  }
  // stage x -> xT bf16 (transpose, packed 2-channel u32 writes)
  for (int idx = tid; idx < 672; idx += 256) {
    int i2 = idx / 12, q = idx - i2 * 12;
    float4 a = *(const float4*)&xb[(size_t)(2 * i2) * HW_ + 4 * q];
    float4 b = *(const float4*)&xb[(size_t)(2 * i2 + 1) * HW_ + 4 * q];
#pragma unroll
    for (int e = 0; e < 4; ++e) {
      unsigned pk = f2bf(f4e(a, e)) | (f2bf(f4e(b, e)) << 16);
      *(unsigned*)&xT[4 * q + 2 + e][2 * i2] = pk;
    }
  }
  // stage wp slice 0 into buf
  for (int idx = tid; idx < 1792; idx += 256) {
    int row = idx >> 4, cq = idx & 15;
    *(float4*)&buf[row][cq * 8] = *(const float4*)&wp[(size_t)row * 128 + cq * 8];
  }
  __syncthreads();

  // ---- conv phase, kx-outer, accs persistent
  f32x4 acc[6];
#pragma unroll
  for (int j = 0; j < 6; ++j) acc[j] = (f32x4){0.f, 0.f, 0.f, 0.f};
  for (int kx = 0; kx < 3; ++kx) {
    if (kx) {
      __syncthreads();  // drain buf reads from previous kx
      for (int idx = tid; idx < 1792; idx += 256) {
        int row = idx >> 4, cq = idx & 15;
        *(float4*)&buf[row][cq * 8] =
            *(const float4*)&wp[(size_t)(kx * 112 + row) * 128 + cq * 8];
      }
      __syncthreads();
    }
#pragma unroll
    for (int j = 0; j < 6; ++j) {
      int t = wv + 4 * j;
      if (t < 21) {
        int m = t / 3, nt = t - 3 * m;
        int o0 = m * 16, w0 = nt * 16;
#pragma unroll
        for (int kb = 0; kb < 4; ++kb) {
          bfrag a = *(const bfrag*)&buf[o0 + lr][8 * lg + 32 * kb];
          bfrag b = *(const bfrag*)&xT[w0 + lr + 2 * kx][8 * lg + 32 * kb];
          acc[j] = __builtin_amdgcn_mfma_f32_16x16x32_bf16(a, b, acc[j], 0, 0, 0);
        }
      }
    }
  }
  // t13 = max(-conv, x)
  unsigned short tv[6][4];
#pragma unroll
  for (int j = 0; j < 6; ++j) {
    int t = wv + 4 * j;
    if (t < 21) {
      int m = t / 3, nt = t - 3 * m;
      int o0 = m * 16, w0 = nt * 16;
#pragma unroll
      for (int e = 0; e < 4; ++e) {
        float xv = bf2f(xT[w0 + lr + 2][o0 + 4 * lg + e]);
        tv[j][e] = (unsigned short)f2bf(fmaxf(-acc[j][e], xv));
      }
    }
  }
  __syncthreads();  // all conv reads of xT/buf complete
  // write t13 into xT; stage G (f32 -> bf16) into buf
#pragma unroll
  for (int j = 0; j < 6; ++j) {
    int t = wv + 4 * j;
    if (t < 21) {
      int m = t / 3, nt = t - 3 * m;
      int o0 = m * 16, w0 = nt * 16;
      unsigned pk0 = (unsigned)tv[j][0] | ((unsigned)tv[j][1] << 16);
      unsigned pk1 = (unsigned)tv[j][2] | ((unsigned)tv[j][3] << 16);
      *(unsigned*)&xT[w0 + lr + 2][o0 + 4 * lg] = pk0;
      *(unsigned*)&xT[w0 + lr + 2][o0 + 4 * lg + 2] = pk1;
    }
  }
  for (int idx = tid; idx < 1792; idx += 256) {
    int row = idx >> 4, cq = idx & 15;
    float4 a = *(const float4*)&gf[(size_t)row * 128 + cq * 8];
    float4 b = *(const float4*)&gf[(size_t)row * 128 + cq * 8 + 4];
    uint4 pk;
    pk.x = f2bf(a.x) | (f2bf(a.y) << 16);
    pk.y = f2bf(a.z) | (f2bf(a.w) << 16);
    pk.z = f2bf(b.x) | (f2bf(b.y) << 16);
    pk.w = f2bf(b.z) | (f2bf(b.w) << 16);
    *(uint4*)&buf[row][cq * 8] = pk;
  }
  __syncthreads();  // t13 + G visible

  // ---- final GEMM: out[c][w] = A'[c] - p19[c]*scale * sum_i S'[c][i]*t13[i][w]
  // (buf col 112 = A'-sum, multiplied by t13 col 112 == 0 -> harmless)
#pragma unroll
  for (int j = 0; j < 6; ++j) {
    int t = wv + 4 * j;
    if (t < 21) {
      int m = t / 3, nt = t - 3 * m;
      int c0 = m * 16, w0 = nt * 16;
      f32x4 acc2 = {0.f, 0.f, 0.f, 0.f};
#pragma unroll
      for (int kb = 0; kb < 4; ++kb) {
        bfrag a = *(const bfrag*)&buf[c0 + lr][8 * lg + 32 * kb];
        bfrag b = *(const bfrag*)&xT[w0 + lr + 2][8 * lg + 32 * kb];
        acc2 = __builtin_amdgcn_mfma_f32_16x16x32_bf16(a, b, acc2, 0, 0, 0);
      }
#pragma unroll
      for (int e = 0; e < 4; ++e) {
        int c = c0 + 4 * lg + e;
        out[((size_t)n * C_ + c) * HW_ + h * W_ + w0 + lr] =
            sA[c] - sP[c] * acc2[e];
      }
    }
  }
}

// ---------------------------------------------------------------------------
extern "C" void kernel_launch(void* const* d_in, const int* in_sizes, int n_in,
                              void* d_out, int out_size, void* d_ws, size_t ws_size,
                              hipStream_t stream) {
  const float* x = (const float*)d_in[0];
  const float* p7 = (const float*)d_in[1];
  // d_in[2] (p8_w) cancels algebraically: t10 = t8 - (x + t8) = -x
  const float* p19 = (const float*)d_in[3];
  const float* cw = (const float*)d_in[4];
  float* ws = (float*)d_ws;
  float* out = (float*)d_out;

  ath_t7<<<dim3(H_, N_), 192, 0, stream>>>(x, p7, ws);
  ath_gram<<<2 * NKS * N_ + 42, 256, 0, stream>>>(x, cw, ws);
  ath_fused<<<dim3(H_, N_), 256, 0, stream>>>(x, p19, ws, out);
}

// Round 19
// 45.588 us; speedup vs baseline: 1.1377x; 1.1377x over previous
//
#include <hip/hip_runtime.h>

typedef __attribute__((ext_vector_type(8))) short bfrag;   // 8 bf16 = 4 VGPR
typedef __attribute__((ext_vector_type(4))) float f32x4;

namespace {
constexpr int N_ = 16, C_ = 112, H_ = 48, W_ = 48, HW_ = 2304;
constexpr int NKS = 18;  // K-slices of 128 (18*128 = 2304)
// ws float offsets
constexpr int WS_T7 = 0;          // 768
constexpr int WS_A = 1024;        // 1792 -> 2816
constexpr int WS_WPACK = 40960;   // 3*112*128 bf16 = 21504 f -> 62464
constexpr int WS_GBF = 62464;     // 16*112*128 bf16 = 114688 f -> 177152
constexpr int WS_SPART = 177152;  // bf16 partials: 18*16*112*128*2B = 8.25MB
}

__device__ __forceinline__ float f4e(const float4& v, int e) {
  return e == 0 ? v.x : e == 1 ? v.y : e == 2 ? v.z : v.w;
}
__device__ __forceinline__ unsigned short f2bf(float f) {  // RNE
  unsigned u = __float_as_uint(f);
  return (unsigned short)((u + 0x7FFFu + ((u >> 16) & 1u)) >> 16);
}
__device__ __forceinline__ float bf2f(unsigned short s) {
  return __uint_as_float(((unsigned)s) << 16);
}

// ---------------------------------------------------------------------------
// K1: t7 as a 48-tap projection of x rows, coalesced: 12 consecutive lanes
// read one contiguous 192B row. t7[n,h'] = (1/112) sum_c dot(x[n,c,h',:], q),
// q[j] = sum_k p7[k][j+3-3k]; value lands at (h'+2)%48 (S3=+1,S6=+1 -> +2).
// grid (48, 16), 192 threads.
__global__ __launch_bounds__(192) void ath_t7(const float* __restrict__ x,
                                              const float* __restrict__ p7,
                                              float* __restrict__ ws) {
  const int h = blockIdx.x, n = blockIdx.y;
  const int tid = threadIdx.x;
  __shared__ float q[48];
  __shared__ float wred[3];
  if (tid < 48) {
    float s = 0.f;
#pragma unroll
    for (int k = 0; k < 3; ++k) {
      int wp = tid + 3 - 3 * k;
      if (wp >= 0 && wp < 48) s += p7[k * 48 + wp];
    }
    q[tid] = s;
  }
  __syncthreads();
  const int c16 = tid / 12, qq = tid - 12 * c16;
  const float qv0 = q[4 * qq], qv1 = q[4 * qq + 1];
  const float qv2 = q[4 * qq + 2], qv3 = q[4 * qq + 3];
  float d = 0.f;
#pragma unroll
  for (int p = 0; p < 7; ++p) {
    const int c = c16 + 16 * p;
    float4 v = *(const float4*)&x[((size_t)n * C_ + c) * HW_ + h * W_ + 4 * qq];
    d += v.x * qv0 + v.y * qv1 + v.z * qv2 + v.w * qv3;
  }
#pragma unroll
  for (int off = 32; off >= 1; off >>= 1) d += __shfl_xor(d, off);
  if ((tid & 63) == 0) wred[tid >> 6] = d;
  __syncthreads();
  if (tid == 0)
    ws[WS_T7 + n * H_ + (h + 2) % 48] =
        (wred[0] + wred[1] + wred[2]) * (1.0f / 112.0f);
}

// ---------------------------------------------------------------------------
// K2: Gram via MFMA, st17-augmented A (LDS) x raw-x B (register-prefetched),
// virtual t7 B-row for A'. Block = (n, ks, half): half owns ti = wv + 4*half.
// t17 recomputed per block from t7 (cheap). SPART stored as bf16.
// Tail blocks: wpack. grid 576 + 42, 256 threads.
__global__ __launch_bounds__(256) void ath_gram(const float* __restrict__ x,
                                                const float* __restrict__ cw,
                                                float* __restrict__ ws) {
  const int bid = blockIdx.x;
  const int tid = threadIdx.x;
  if (bid >= 2 * NKS * N_) {  // ---- wpack tail: bf16 [kx][o][i pad 128]
    int idx = (bid - 2 * NKS * N_) * 256 + tid;
    if (idx < 3 * 112 * 32) {
      int kx = idx / (112 * 32);
      int r = idx - kx * 112 * 32;
      int o = r >> 5;
      int i0 = (r & 31) * 4;
      unsigned short v[4];
#pragma unroll
      for (int e = 0; e < 4; ++e) {
        int i = i0 + e;
        v[e] = (i < 112) ? f2bf(cw[o * 336 + i * 3 + kx]) : (unsigned short)0;
      }
      unsigned short* wp = (unsigned short*)(ws + WS_WPACK);
      *(ushort4*)&wp[(kx * 112 + o) * 128 + i0] = make_ushort4(v[0], v[1], v[2], v[3]);
    }
    return;
  }
  const int half = bid & 1;
  const int ks = (bid >> 1) % NKS;
  const int n = bid / (2 * NKS);
  const int k0 = ks * 128;
  const int lane = tid & 63, wv = tid >> 6;
  const int lr = lane & 15, lg = lane >> 4;
  __shared__ __align__(16) unsigned short As[112][136];
  __shared__ __align__(16) unsigned short t7r[136];
  __shared__ float t7s[48];
  __shared__ float s17[8];
  if (tid < 48) t7s[tid] = ws[WS_T7 + n * H_ + tid];
  __syncthreads();
  if (tid < 7) {  // t17[kk] = (1/48) sum_h |t7pad[2kk+h-6]|
    float s = 0.f;
    for (int hh = 0; hh < 48; ++hh) {
      int j = 2 * tid + hh - 6;
      if (j >= 0 && j < 48) s += fabsf(t7s[j]);
    }
    s17[tid] = s * (1.0f / 48.0f);
  }
  if (tid >= 64 && tid < 192) t7r[tid - 64] = f2bf(t7s[(k0 + tid - 64) / 48]);
  if (tid >= 192 && tid < 200) t7r[128 + (tid - 192)] = 0;
  // prefetch B fragments into registers (no LDS dependency; overlaps)
  const int ti = wv + 4 * half;  // this wave's output column-group (0..7)
  bfrag breg[4];
  if (ti < 7) {
    const float* bp = &x[((size_t)n * C_ + 16 * ti + lr) * HW_ + k0 + 8 * lg];
#pragma unroll
    for (int kb = 0; kb < 4; ++kb) {
      float4 v0 = *(const float4*)(bp + 32 * kb);
      float4 v1 = *(const float4*)(bp + 32 * kb + 4);
      breg[kb][0] = (short)f2bf(v0.x); breg[kb][1] = (short)f2bf(v0.y);
      breg[kb][2] = (short)f2bf(v0.z); breg[kb][3] = (short)f2bf(v0.w);
      breg[kb][4] = (short)f2bf(v1.x); breg[kb][5] = (short)f2bf(v1.y);
      breg[kb][6] = (short)f2bf(v1.z); breg[kb][7] = (short)f2bf(v1.w);
    }
  }
  __syncthreads();  // s17/t7r visible to ALL waves before A staging reads s17
  // stage augmented A: As[c][p-k0] = bf16(x[c,p] + s17[(c+p)%7])
  const int kq = tid & 31, cg2 = tid >> 5;
  const int base7 = (k0 + 4 * kq) % 7;
#pragma unroll
  for (int r = 0; r < 14; ++r) {
    const int c = cg2 + 8 * r;
    float4 v = *(const float4*)&x[((size_t)n * C_ + c) * HW_ + k0 + 4 * kq];
    int cls0 = (base7 + c) % 7;
    unsigned short a4[4];
#pragma unroll
    for (int e = 0; e < 4; ++e) {
      int cl = cls0 + e;
      cl = (cl >= 7) ? cl - 7 : cl;
      a4[e] = f2bf(f4e(v, e) + s17[cl]);
    }
    *(ushort4*)&As[c][4 * kq] = make_ushort4(a4[0], a4[1], a4[2], a4[3]);
  }
  __syncthreads();
  if (ti == 7) {
    const bfrag zero8 = {0, 0, 0, 0, 0, 0, 0, 0};
#pragma unroll
    for (int kb = 0; kb < 4; ++kb)
      breg[kb] = (lr == 0) ? *(const bfrag*)&t7r[8 * lg + 32 * kb] : zero8;
  }
  f32x4 acc[7];
#pragma unroll
  for (int j = 0; j < 7; ++j) acc[j] = (f32x4){0.f, 0.f, 0.f, 0.f};
#pragma unroll
  for (int kb = 0; kb < 4; ++kb) {
#pragma unroll
    for (int tc = 0; tc < 7; ++tc) {
      bfrag a = *(const bfrag*)&As[16 * tc + lr][8 * lg + 32 * kb];
      acc[tc] = __builtin_amdgcn_mfma_f32_16x16x32_bf16(a, breg[kb], acc[tc], 0, 0, 0);
    }
  }
  unsigned short* sp =
      (unsigned short*)(ws + WS_SPART) + (size_t)(n * NKS + ks) * 14336;
#pragma unroll
  for (int tc = 0; tc < 7; ++tc)
#pragma unroll
    for (int e = 0; e < 4; ++e)
      sp[(16 * tc + 4 * lg + e) * 128 + 16 * ti + lr] = f2bf(acc[tc][e]);
}

// ---------------------------------------------------------------------------
// K3: reduce bf16 SPART -> Gbf (bf16, cols>=112 zero) + A'. f32 accumulate.
// grid N*28, 128 thr.
__global__ __launch_bounds__(128) void ath_assemble(const float* __restrict__ p19,
                                                    float* __restrict__ ws) {
  const int bid = blockIdx.x;
  const int n = bid / 28, g = bid % 28;
  const int tid = threadIdx.x;
  const int cloc = tid >> 5, q = tid & 31;
  const int c = 4 * g + cloc;
  const int i0 = 4 * q;
  const unsigned short* spb = (const unsigned short*)(ws + WS_SPART);
  float s0 = 0.f, s1 = 0.f, s2 = 0.f, s3 = 0.f;
#pragma unroll
  for (int ks = 0; ks < NKS; ++ks) {
    ushort4 t = *(const ushort4*)&spb[(size_t)(n * NKS + ks) * 14336 + c * 128 + i0];
    s0 += bf2f(t.x); s1 += bf2f(t.y); s2 += bf2f(t.z); s3 += bf2f(t.w);
  }
  unsigned short* gb = (unsigned short*)(ws + WS_GBF);
  if (i0 < 112) {
    const float scale = 1.0f / (48.0f * sqrtf(112.0f));
    const float pc = p19[c];
    *(ushort4*)&gb[((size_t)n * C_ + c) * 128 + i0] =
        make_ushort4(f2bf(pc * s0 * scale), f2bf(pc * s1 * scale),
                     f2bf(pc * s2 * scale), f2bf(pc * s3 * scale));
  } else {
    *(ushort4*)&gb[((size_t)n * C_ + c) * 128 + i0] = make_ushort4(0, 0, 0, 0);
    if (i0 == 112) ws[WS_A + n * C_ + c] = p19[c] * s0 * (2.0f / 48.0f);
  }
}

// ---------------------------------------------------------------------------
// K4 fused via MFMA, LDS-stationary operands (R13/R16 structure: stage loops
// between barriers; loads NOT held across the MFMA phase — reg-held prefetch
// crosses the 128-VGPR cliff and costs a block/CU, R14 post-mortem).
// xT[52][136] bf16 transposed x-slab; buf[112][136] = wp slice kx, then Gbf.
// t13 in-place into xT. 21 16x16 tiles round-robin over 4 waves. LDS ~45 KB.
__global__ __launch_bounds__(256) void ath_fused(const float* __restrict__ x,
                                                 const float* __restrict__ ws,
                                                 float* __restrict__ out) {
  const int h = blockIdx.x, n = blockIdx.y;
  const int tid = threadIdx.x;
  const int lane = tid & 63, wv = tid >> 6;
  const int lr = lane & 15, lg = lane >> 4;
  __shared__ __align__(16) unsigned short xT[52][136];
  __shared__ __align__(16) unsigned short buf[112][136];
  __shared__ float sA[112];
  const float* xb = x + (size_t)n * C_ * HW_ + h * W_;
  const unsigned short* wp = (const unsigned short*)(ws + WS_WPACK);
  const unsigned short* gb = (const unsigned short*)(ws + WS_GBF) + (size_t)n * C_ * 128;
  for (int idx = tid; idx < 52 * 24; idx += 256) {
    int r2 = idx / 24, cc = 112 + idx % 24;
    xT[r2][cc] = 0;
  }
  for (int idx = tid; idx < 4 * 112; idx += 256) {
    int rr = idx / 112;
    int r2 = (rr < 2) ? rr : 48 + rr;
    xT[r2][idx % 112] = 0;
  }
  if (tid < 112) sA[tid] = ws[WS_A + n * C_ + tid];
  for (int idx = tid; idx < 672; idx += 256) {
    int i2 = idx / 12, q = idx - i2 * 12;
    float4 a = *(const float4*)&xb[(size_t)(2 * i2) * HW_ + 4 * q];
    float4 b = *(const float4*)&xb[(size_t)(2 * i2 + 1) * HW_ + 4 * q];
#pragma unroll
    for (int e = 0; e < 4; ++e) {
      unsigned pk = (unsigned)f2bf(f4e(a, e)) | ((unsigned)f2bf(f4e(b, e)) << 16);
      *(unsigned*)&xT[4 * q + 2 + e][2 * i2] = pk;
    }
  }
  for (int idx = tid; idx < 1792; idx += 256) {
    int row = idx >> 4, cq = idx & 15;
    *(float4*)&buf[row][cq * 8] = *(const float4*)&wp[(size_t)row * 128 + cq * 8];
  }
  __syncthreads();

  f32x4 acc[6];
#pragma unroll
  for (int j = 0; j < 6; ++j) acc[j] = (f32x4){0.f, 0.f, 0.f, 0.f};
  for (int kx = 0; kx < 3; ++kx) {
    if (kx) {
      __syncthreads();
      for (int idx = tid; idx < 1792; idx += 256) {
        int row = idx >> 4, cq = idx & 15;
        *(float4*)&buf[row][cq * 8] =
            *(const float4*)&wp[(size_t)(kx * 112 + row) * 128 + cq * 8];
      }
      __syncthreads();
    }
#pragma unroll
    for (int j = 0; j < 6; ++j) {
      int t = wv + 4 * j;
      if (t < 21) {
        int m = t / 3, nt = t - 3 * m;
        int o0 = m * 16, w0 = nt * 16;
#pragma unroll
        for (int kb = 0; kb < 4; ++kb) {
          bfrag a = *(const bfrag*)&buf[o0 + lr][8 * lg + 32 * kb];
          bfrag b = *(const bfrag*)&xT[w0 + lr + 2 * kx][8 * lg + 32 * kb];
          acc[j] = __builtin_amdgcn_mfma_f32_16x16x32_bf16(a, b, acc[j], 0, 0, 0);
        }
      }
    }
  }
  unsigned short tv[6][4];
#pragma unroll
  for (int j = 0; j < 6; ++j) {
    int t = wv + 4 * j;
    if (t < 21) {
      int m = t / 3, nt = t - 3 * m;
      int o0 = m * 16, w0 = nt * 16;
#pragma unroll
      for (int e = 0; e < 4; ++e) {
        float xv = bf2f(xT[w0 + lr + 2][o0 + 4 * lg + e]);
        tv[j][e] = f2bf(fmaxf(-acc[j][e], xv));
      }
    }
  }
  __syncthreads();
#pragma unroll
  for (int j = 0; j < 6; ++j) {
    int t = wv + 4 * j;
    if (t < 21) {
      int m = t / 3, nt = t - 3 * m;
      int o0 = m * 16, w0 = nt * 16;
      unsigned pk0 = (unsigned)tv[j][0] | ((unsigned)tv[j][1] << 16);
      unsigned pk1 = (unsigned)tv[j][2] | ((unsigned)tv[j][3] << 16);
      *(unsigned*)&xT[w0 + lr + 2][o0 + 4 * lg] = pk0;
      *(unsigned*)&xT[w0 + lr + 2][o0 + 4 * lg + 2] = pk1;
    }
  }
  for (int idx = tid; idx < 1792; idx += 256) {
    int row = idx >> 4, cq = idx & 15;
    *(float4*)&buf[row][cq * 8] = *(const float4*)&gb[(size_t)row * 128 + cq * 8];
  }
  __syncthreads();
#pragma unroll
  for (int j = 0; j < 6; ++j) {
    int t = wv + 4 * j;
    if (t < 21) {
      int m = t / 3, nt = t - 3 * m;
      int c0 = m * 16, w0 = nt * 16;
      f32x4 acc2 = {0.f, 0.f, 0.f, 0.f};
#pragma unroll
      for (int kb = 0; kb < 4; ++kb) {
        bfrag a = *(const bfrag*)&buf[c0 + lr][8 * lg + 32 * kb];
        bfrag b = *(const bfrag*)&xT[w0 + lr + 2][8 * lg + 32 * kb];
        acc2 = __builtin_amdgcn_mfma_f32_16x16x32_bf16(a, b, acc2, 0, 0, 0);
      }
#pragma unroll
      for (int e = 0; e < 4; ++e) {
        int c = c0 + 4 * lg + e;
        out[((size_t)n * C_ + c) * HW_ + h * W_ + w0 + lr] = sA[c] - acc2[e];
      }
    }
  }
}

// ---------------------------------------------------------------------------
extern "C" void kernel_launch(void* const* d_in, const int* in_sizes, int n_in,
                              void* d_out, int out_size, void* d_ws, size_t ws_size,
                              hipStream_t stream) {
  const float* x = (const float*)d_in[0];
  const float* p7 = (const float*)d_in[1];
  // d_in[2] (p8_w) cancels algebraically: t10 = t8 - (x + t8) = -x
  const float* p19 = (const float*)d_in[3];
  const float* cw = (const float*)d_in[4];
  float* ws = (float*)d_ws;
  float* out = (float*)d_out;

  ath_t7<<<dim3(H_, N_), 192, 0, stream>>>(x, p7, ws);
  ath_gram<<<2 * NKS * N_ + 42, 256, 0, stream>>>(x, cw, ws);
  ath_assemble<<<N_ * 28, 128, 0, stream>>>(p19, ws);
  ath_fused<<<dim3(H_, N_), 256, 0, stream>>>(x, ws, out);
}